// Round 3
// baseline (1672.268 us; speedup 1.0000x reference)
//
#include <hip/hip_runtime.h>

#define TOK 4096
#define NE 16
#define HD 2048
#define ID 1024
#define QGROUP 16
#define CAP 4096
#define BM 8

__device__ __forceinline__ unsigned short f2bf(float f) {
    unsigned int u = __float_as_uint(f);
    unsigned int r = (u + 0x7fffu + ((u >> 16) & 1u)) >> 16;
    return (unsigned short)r;
}
__device__ __forceinline__ float bf2f(unsigned int u) {
    return __uint_as_float(u << 16);
}

// ---------------- router ----------------
__global__ __launch_bounds__(256) void router_kernel(
    const float* __restrict__ x, const float* __restrict__ gw,
    int* __restrict__ counts, int* __restrict__ pair_row, float* __restrict__ pair_w)
{
    int t = blockIdx.x;
    int tid = threadIdx.x;
    float p[NE];
#pragma unroll
    for (int e = 0; e < NE; e++) p[e] = 0.f;
    const float* xr = x + (size_t)t * HD;
    for (int h = tid; h < HD; h += 256) {
        float xv = xr[h];
#pragma unroll
        for (int e = 0; e < NE; e++) p[e] = fmaf(xv, gw[e * HD + h], p[e]);
    }
#pragma unroll
    for (int off = 32; off > 0; off >>= 1) {
#pragma unroll
        for (int e = 0; e < NE; e++) p[e] += __shfl_down(p[e], off, 64);
    }
    __shared__ float part[4][NE];
    int wave = tid >> 6, lane = tid & 63;
    if (lane == 0) {
#pragma unroll
        for (int e = 0; e < NE; e++) part[wave][e] = p[e];
    }
    __syncthreads();
    if (tid == 0) {
        float s[NE]; float sum = 0.f;
#pragma unroll
        for (int e = 0; e < NE; e++) {
            float l = part[0][e] + part[1][e] + part[2][e] + part[3][e];
            float sg = 1.f / (1.f + expf(-l));
            s[e] = sg; sum += sg;
        }
        int i1 = 0;
#pragma unroll
        for (int e = 1; e < NE; e++) if (s[e] > s[i1]) i1 = e;
        int i2 = (i1 == 0) ? 1 : 0;
#pragma unroll
        for (int e = 0; e < NE; e++) if (e != i1 && s[e] > s[i2]) i2 = e;
        float p1 = s[i1] / sum, p2 = s[i2] / sum;
        float inv = 1.f / (p1 + p2 + 1e-20f);
        float w1 = p1 * inv, w2 = p2 * inv;
        int s1 = atomicAdd(&counts[i1], 1);
        pair_row[i1 * CAP + s1] = t * 2;     pair_w[i1 * CAP + s1] = w1;
        int s2 = atomicAdd(&counts[i2], 1);
        pair_row[i2 * CAP + s2] = t * 2 + 1; pair_w[i2 * CAP + s2] = w2;
    }
}

// ---------------- up proj + relu^2 * routing weight ----------------
__global__ __launch_bounds__(256) void up_kernel(
    const float* __restrict__ x, const int* __restrict__ qw,
    const float* __restrict__ bsc, const float* __restrict__ gsc,
    const int* __restrict__ counts, const int* __restrict__ pair_row,
    const float* __restrict__ pair_w, unsigned short* __restrict__ act)
{
    const int e = blockIdx.y;
    const int base = blockIdx.x * BM;
    const int cnt = counts[e];
    if (base >= cnt) return;
    const int nrow = min(BM, cnt - base);
    const int tid = threadIdx.x;

    __shared__ int rows_s[BM];
    __shared__ float pw_s[BM];
    __shared__ float xs[BM][256];

    if (tid < BM) {
        int r = (tid < nrow) ? (base + tid) : base;
        rows_s[tid] = pair_row[e * CAP + r];
        pw_s[tid]   = pair_w[e * CAP + r];
    }

    float4 acc[BM];
#pragma unroll
    for (int r = 0; r < BM; r++) acc[r] = make_float4(0.f, 0.f, 0.f, 0.f);

    const int i0 = tid * 4;
    const int lrow = tid >> 5;
    const int lcol = (tid & 31) * 8;

    for (int h0 = 0; h0 < HD; h0 += 256) {
        __syncthreads();
        {
            int trow = rows_s[lrow] >> 1;
            const float* src = x + (size_t)trow * HD + h0 + lcol;
            float4 a0 = *(const float4*)src;
            float4 a1 = *(const float4*)(src + 4);
            *(float4*)&xs[lrow][lcol]     = a0;
            *(float4*)&xs[lrow][lcol + 4] = a1;
        }
        __syncthreads();
        for (int hh = 0; hh < 256; hh += 16) {
            const int g = (h0 + hh) >> 4;
            const float4 sc = *(const float4*)&bsc[(size_t)(e * (HD / QGROUP) + g) * ID + i0];
            for (int hs = 0; hs < 16; hs += 4) {
                const int hb = hh + hs;
                const int habs = h0 + hb;
                int4 c0 = *(const int4*)&qw[(size_t)(e * HD + habs + 0) * ID + i0];
                int4 c1 = *(const int4*)&qw[(size_t)(e * HD + habs + 1) * ID + i0];
                int4 c2 = *(const int4*)&qw[(size_t)(e * HD + habs + 2) * ID + i0];
                int4 c3 = *(const int4*)&qw[(size_t)(e * HD + habs + 3) * ID + i0];
                float4 w0 = make_float4((float)(c0.x - 8) * sc.x, (float)(c0.y - 8) * sc.y,
                                        (float)(c0.z - 8) * sc.z, (float)(c0.w - 8) * sc.w);
                float4 w1 = make_float4((float)(c1.x - 8) * sc.x, (float)(c1.y - 8) * sc.y,
                                        (float)(c1.z - 8) * sc.z, (float)(c1.w - 8) * sc.w);
                float4 w2 = make_float4((float)(c2.x - 8) * sc.x, (float)(c2.y - 8) * sc.y,
                                        (float)(c2.z - 8) * sc.z, (float)(c2.w - 8) * sc.w);
                float4 w3 = make_float4((float)(c3.x - 8) * sc.x, (float)(c3.y - 8) * sc.y,
                                        (float)(c3.z - 8) * sc.z, (float)(c3.w - 8) * sc.w);
#pragma unroll
                for (int r = 0; r < BM; r++) {
                    float4 xv = *(const float4*)&xs[r][hb];
                    acc[r].x = fmaf(xv.x, w0.x, acc[r].x); acc[r].x = fmaf(xv.y, w1.x, acc[r].x);
                    acc[r].x = fmaf(xv.z, w2.x, acc[r].x); acc[r].x = fmaf(xv.w, w3.x, acc[r].x);
                    acc[r].y = fmaf(xv.x, w0.y, acc[r].y); acc[r].y = fmaf(xv.y, w1.y, acc[r].y);
                    acc[r].y = fmaf(xv.z, w2.y, acc[r].y); acc[r].y = fmaf(xv.w, w3.y, acc[r].y);
                    acc[r].z = fmaf(xv.x, w0.z, acc[r].z); acc[r].z = fmaf(xv.y, w1.z, acc[r].z);
                    acc[r].z = fmaf(xv.z, w2.z, acc[r].z); acc[r].z = fmaf(xv.w, w3.z, acc[r].z);
                    acc[r].w = fmaf(xv.x, w0.w, acc[r].w); acc[r].w = fmaf(xv.y, w1.w, acc[r].w);
                    acc[r].w = fmaf(xv.z, w2.w, acc[r].w); acc[r].w = fmaf(xv.w, w3.w, acc[r].w);
                }
            }
        }
    }
    const float gs = gsc[0];
#pragma unroll
    for (int r = 0; r < BM; r++) {
        if (r < nrow) {
            float pw = pw_s[r];
            int row = rows_s[r];
            float z0 = acc[r].x * gs, z1 = acc[r].y * gs, z2 = acc[r].z * gs, z3 = acc[r].w * gs;
            float a0 = fmaxf(z0, 0.f); a0 = a0 * a0 * pw;
            float a1 = fmaxf(z1, 0.f); a1 = a1 * a1 * pw;
            float a2 = fmaxf(z2, 0.f); a2 = a2 * a2 * pw;
            float a3 = fmaxf(z3, 0.f); a3 = a3 * a3 * pw;
            ushort4 o = make_ushort4(f2bf(a0), f2bf(a1), f2bf(a2), f2bf(a3));
            *(ushort4*)&act[(size_t)row * ID + i0] = o;
        }
    }
}

// ---------------- down proj (per-pair rows, no atomics) ----------------
__global__ __launch_bounds__(256) void down_kernel(
    const unsigned short* __restrict__ act, const int* __restrict__ qw,
    const float* __restrict__ bsc, const float* __restrict__ gsc,
    const int* __restrict__ counts, const int* __restrict__ pair_row,
    unsigned short* __restrict__ ydown)
{
    const int e = blockIdx.y;
    const int ntile = blockIdx.x & 1;
    const int base = (blockIdx.x >> 1) * BM;
    const int cnt = counts[e];
    if (base >= cnt) return;
    const int nrow = min(BM, cnt - base);
    const int tid = threadIdx.x;

    __shared__ int rows_s[BM];
    __shared__ float xs[BM][256];

    if (tid < BM) {
        int r = (tid < nrow) ? (base + tid) : base;
        rows_s[tid] = pair_row[e * CAP + r];
    }

    float4 acc[BM];
#pragma unroll
    for (int r = 0; r < BM; r++) acc[r] = make_float4(0.f, 0.f, 0.f, 0.f);

    const int i0 = ntile * 1024 + tid * 4;   // column in H
    const int lrow = tid >> 5;
    const int lcol = (tid & 31) * 8;

    for (int k0 = 0; k0 < ID; k0 += 256) {
        __syncthreads();
        {
            int row = rows_s[lrow];
            const unsigned short* src = act + (size_t)row * ID + k0 + lcol;
            uint4 raw = *(const uint4*)src;  // 8 bf16
            xs[lrow][lcol + 0] = bf2f(raw.x & 0xffffu);
            xs[lrow][lcol + 1] = bf2f(raw.x >> 16);
            xs[lrow][lcol + 2] = bf2f(raw.y & 0xffffu);
            xs[lrow][lcol + 3] = bf2f(raw.y >> 16);
            xs[lrow][lcol + 4] = bf2f(raw.z & 0xffffu);
            xs[lrow][lcol + 5] = bf2f(raw.z >> 16);
            xs[lrow][lcol + 6] = bf2f(raw.w & 0xffffu);
            xs[lrow][lcol + 7] = bf2f(raw.w >> 16);
        }
        __syncthreads();
        for (int kk = 0; kk < 256; kk += 16) {
            const int g = (k0 + kk) >> 4;
            const float4 sc = *(const float4*)&bsc[(size_t)(e * (ID / QGROUP) + g) * HD + i0];
            for (int ks = 0; ks < 16; ks += 4) {
                const int kb = kk + ks;
                const int kabs = k0 + kb;
                int4 c0 = *(const int4*)&qw[(size_t)(e * ID + kabs + 0) * HD + i0];
                int4 c1 = *(const int4*)&qw[(size_t)(e * ID + kabs + 1) * HD + i0];
                int4 c2 = *(const int4*)&qw[(size_t)(e * ID + kabs + 2) * HD + i0];
                int4 c3 = *(const int4*)&qw[(size_t)(e * ID + kabs + 3) * HD + i0];
                float4 w0 = make_float4((float)(c0.x - 8) * sc.x, (float)(c0.y - 8) * sc.y,
                                        (float)(c0.z - 8) * sc.z, (float)(c0.w - 8) * sc.w);
                float4 w1 = make_float4((float)(c1.x - 8) * sc.x, (float)(c1.y - 8) * sc.y,
                                        (float)(c1.z - 8) * sc.z, (float)(c1.w - 8) * sc.w);
                float4 w2 = make_float4((float)(c2.x - 8) * sc.x, (float)(c2.y - 8) * sc.y,
                                        (float)(c2.z - 8) * sc.z, (float)(c2.w - 8) * sc.w);
                float4 w3 = make_float4((float)(c3.x - 8) * sc.x, (float)(c3.y - 8) * sc.y,
                                        (float)(c3.z - 8) * sc.z, (float)(c3.w - 8) * sc.w);
#pragma unroll
                for (int r = 0; r < BM; r++) {
                    float4 xv = *(const float4*)&xs[r][kb];
                    acc[r].x = fmaf(xv.x, w0.x, acc[r].x); acc[r].x = fmaf(xv.y, w1.x, acc[r].x);
                    acc[r].x = fmaf(xv.z, w2.x, acc[r].x); acc[r].x = fmaf(xv.w, w3.x, acc[r].x);
                    acc[r].y = fmaf(xv.x, w0.y, acc[r].y); acc[r].y = fmaf(xv.y, w1.y, acc[r].y);
                    acc[r].y = fmaf(xv.z, w2.y, acc[r].y); acc[r].y = fmaf(xv.w, w3.y, acc[r].y);
                    acc[r].z = fmaf(xv.x, w0.z, acc[r].z); acc[r].z = fmaf(xv.y, w1.z, acc[r].z);
                    acc[r].z = fmaf(xv.z, w2.z, acc[r].z); acc[r].z = fmaf(xv.w, w3.z, acc[r].z);
                    acc[r].w = fmaf(xv.x, w0.w, acc[r].w); acc[r].w = fmaf(xv.y, w1.w, acc[r].w);
                    acc[r].w = fmaf(xv.z, w2.w, acc[r].w); acc[r].w = fmaf(xv.w, w3.w, acc[r].w);
                }
            }
        }
    }
    const float gs = gsc[0];
#pragma unroll
    for (int r = 0; r < BM; r++) {
        if (r < nrow) {
            int row = rows_s[r];
            ushort4 o = make_ushort4(f2bf(acc[r].x * gs), f2bf(acc[r].y * gs),
                                     f2bf(acc[r].z * gs), f2bf(acc[r].w * gs));
            *(ushort4*)&ydown[(size_t)row * HD + i0] = o;
        }
    }
}

// ---------------- combine the two pair rows per token (fp32 output) ----------------
__global__ __launch_bounds__(256) void finalize_kernel(
    const unsigned short* __restrict__ ydown, float* __restrict__ out)
{
    int i = (blockIdx.x * 256 + threadIdx.x) * 4;   // index in [TOK*HD)
    int t = i >> 11;
    int h = i & 2047;
    size_t a = ((size_t)t << 12) + h;               // row 2t
    uint2 ra = *(const uint2*)&ydown[a];
    uint2 rb = *(const uint2*)&ydown[a + HD];
    float4 o;
    o.x = bf2f(ra.x & 0xffffu) + bf2f(rb.x & 0xffffu);
    o.y = bf2f(ra.x >> 16)     + bf2f(rb.x >> 16);
    o.z = bf2f(ra.y & 0xffffu) + bf2f(rb.y & 0xffffu);
    o.w = bf2f(ra.y >> 16)     + bf2f(rb.y >> 16);
    *(float4*)&out[i] = o;
}

extern "C" void kernel_launch(void* const* d_in, const int* in_sizes, int n_in,
                              void* d_out, int out_size, void* d_ws, size_t ws_size,
                              hipStream_t stream) {
    const float* x   = (const float*)d_in[0];
    const float* gw  = (const float*)d_in[1];
    const float* usc = (const float*)d_in[2];
    const float* ugs = (const float*)d_in[3];
    const float* dsc = (const float*)d_in[4];
    const float* dgs = (const float*)d_in[5];
    const int*   uq  = (const int*)d_in[6];
    const int*   dq  = (const int*)d_in[7];
    float* out = (float*)d_out;

    char* ws = (char*)d_ws;
    // layout: counts | pair_row | pair_w | act(bf16) | ydown(bf16)
    int*   counts   = (int*)(ws + 0);
    int*   pair_row = (int*)(ws + 4096);
    float* pair_w   = (float*)(ws + 4096 + (size_t)NE * CAP * 4);            // 266240
    unsigned short* act   = (unsigned short*)(ws + 528384);                  // 2*TOK*ID bf16
    unsigned short* ydown = (unsigned short*)(ws + 528384 + (size_t)2 * TOK * ID * 2); // 17305600

    hipMemsetAsync(counts, 0, 4096, stream);
    router_kernel<<<TOK, 256, 0, stream>>>(x, gw, counts, pair_row, pair_w);
    up_kernel<<<dim3(CAP / BM, NE), 256, 0, stream>>>(x, uq, usc, ugs, counts, pair_row, pair_w, act);
    down_kernel<<<dim3(2 * (CAP / BM), NE), 256, 0, stream>>>(act, dq, dsc, dgs, counts, pair_row, ydown);
    finalize_kernel<<<(TOK * HD) / 1024, 256, 0, stream>>>(ydown, out);
}

// Round 4
// 605.424 us; speedup vs baseline: 2.7621x; 2.7621x over previous
//
#include <hip/hip_runtime.h>

#define TOK 4096
#define NE 16
#define HD 2048
#define ID 1024
#define QGROUP 16
#define CAP 4096

typedef _Float16 half4v __attribute__((ext_vector_type(4)));
typedef _Float16 half8v __attribute__((ext_vector_type(8)));
typedef float float4v __attribute__((ext_vector_type(4)));

__device__ __forceinline__ float bf2f(unsigned int u) { return __uint_as_float(u << 16); }

// ---------------- prep: x fp32 -> f16 ----------------
__global__ __launch_bounds__(256) void prep_kernel(
    const float* __restrict__ x, _Float16* __restrict__ xh)
{
    int i8 = (blockIdx.x * 256 + threadIdx.x) * 8;
    float4 f0 = *(const float4*)&x[i8];
    float4 f1 = *(const float4*)&x[i8 + 4];
    half8v h;
    h[0] = (_Float16)f0.x; h[1] = (_Float16)f0.y; h[2] = (_Float16)f0.z; h[3] = (_Float16)f0.w;
    h[4] = (_Float16)f1.x; h[5] = (_Float16)f1.y; h[6] = (_Float16)f1.z; h[7] = (_Float16)f1.w;
    *(half8v*)&xh[i8] = h;
}

// ---------------- router ----------------
__global__ __launch_bounds__(256) void router_kernel(
    const float* __restrict__ x, const float* __restrict__ gw,
    int* __restrict__ counts, int* __restrict__ pair_row, float* __restrict__ pair_w)
{
    int t = blockIdx.x;
    int tid = threadIdx.x;
    float p[NE];
#pragma unroll
    for (int e = 0; e < NE; e++) p[e] = 0.f;
    const float* xr = x + (size_t)t * HD;
    for (int h = tid; h < HD; h += 256) {
        float xv = xr[h];
#pragma unroll
        for (int e = 0; e < NE; e++) p[e] = fmaf(xv, gw[e * HD + h], p[e]);
    }
#pragma unroll
    for (int off = 32; off > 0; off >>= 1) {
#pragma unroll
        for (int e = 0; e < NE; e++) p[e] += __shfl_down(p[e], off, 64);
    }
    __shared__ float part[4][NE];
    int wave = tid >> 6, lane = tid & 63;
    if (lane == 0) {
#pragma unroll
        for (int e = 0; e < NE; e++) part[wave][e] = p[e];
    }
    __syncthreads();
    if (tid == 0) {
        float s[NE]; float sum = 0.f;
#pragma unroll
        for (int e = 0; e < NE; e++) {
            float l = part[0][e] + part[1][e] + part[2][e] + part[3][e];
            float sg = 1.f / (1.f + expf(-l));
            s[e] = sg; sum += sg;
        }
        int i1 = 0;
#pragma unroll
        for (int e = 1; e < NE; e++) if (s[e] > s[i1]) i1 = e;
        int i2 = (i1 == 0) ? 1 : 0;
#pragma unroll
        for (int e = 0; e < NE; e++) if (e != i1 && s[e] > s[i2]) i2 = e;
        float p1 = s[i1] / sum, p2 = s[i2] / sum;
        float inv = 1.f / (p1 + p2 + 1e-20f);
        float w1 = p1 * inv, w2 = p2 * inv;
        int s1 = atomicAdd(&counts[i1], 1);
        pair_row[i1 * CAP + s1] = t * 2;     pair_w[i1 * CAP + s1] = w1;
        int s2 = atomicAdd(&counts[i2], 1);
        pair_row[i2 * CAP + s2] = t * 2 + 1; pair_w[i2 * CAP + s2] = w2;
    }
}

// ---------------- grouped MFMA GEMM (shared by up & down) ----------------
// A: f16 source rows; up: row = pair>>1 into xh[TOK][K]; down: row = pair into act[2*TOK][K]
// B: int codes [E][K][N], scales [E][K/16][N]; D = dequant(B)
// UP epilogue: act = (relu(z*gs))^2 * pw -> store16[pair][N]
// DOWN: v = z*gs -> store16[pair][N] (ydown path) or atomicAdd(store32[pair>>1][N]) path
template<int N, int K, bool UP>
__global__ __launch_bounds__(256) void gemm_kernel(
    const _Float16* __restrict__ A, const int* __restrict__ qw,
    const float* __restrict__ bsc, const float* __restrict__ gsc,
    const int* __restrict__ counts, const int* __restrict__ pair_row,
    const float* __restrict__ pair_w,
    _Float16* __restrict__ store16, float* __restrict__ store32)
{
    constexpr int NT = N / 128;
    const int e = blockIdx.y;
    const int cnt = counts[e];
    const int mt = blockIdx.x / NT, nt = blockIdx.x % NT;
    const int mbase = mt * 128;
    if (mbase >= cnt) return;
    const int nbase = nt * 128;
    const int tid = threadIdx.x;

    __shared__ _Float16 As[128][40];   // [m][k], stride 40 f16 = 80 B
    __shared__ _Float16 Bs[128][40];   // [n][k]
    __shared__ int rows_s[128];
    __shared__ float pw_s[128];

    if (tid < 128) {
        int idx = mbase + tid; if (idx >= cnt) idx = cnt - 1;
        rows_s[tid] = pair_row[e * CAP + idx];
        pw_s[tid] = UP ? pair_w[e * CAP + idx] : 0.f;
    }

    const int lane = tid & 63, wv = tid >> 6;
    const int quad = lane >> 4, lm = lane & 15;
    const int wr = (wv >> 1) * 64, wc = (wv & 1) * 64;

    float4v acc[4][4];
#pragma unroll
    for (int mi = 0; mi < 4; mi++)
#pragma unroll
        for (int ni = 0; ni < 4; ni++) acc[mi][ni] = (float4v){0.f, 0.f, 0.f, 0.f};

    const int am = tid & 127, akk = (tid >> 7) * 16;
    const int bn4 = (tid & 31) * 4, bkb = (tid >> 5) * 4;

    for (int k0 = 0; k0 < K; k0 += 32) {
        __syncthreads();
        // ---- stage A (gathered f16 rows) ----
        {
            int pr = rows_s[am];
            int row = UP ? (pr >> 1) : pr;
            const _Float16* src = A + (size_t)row * K + k0 + akk;
            uint4 r0 = *(const uint4*)src;
            uint4 r1 = *(const uint4*)(src + 8);
            *(uint4*)&As[am][akk] = r0;
            *(uint4*)&As[am][akk + 8] = r1;
        }
        // ---- stage B (dequant int4 codes -> f16, transposed [n][k]) ----
        {
            const int kabs = k0 + bkb;
            const int g = kabs >> 4;   // bkb%16 in {0,4,8,12}: rows kabs..kabs+3 same group
            const float4 sc = *(const float4*)&bsc[((size_t)e * (K / QGROUP) + g) * N + nbase + bn4];
            const int4 c0 = *(const int4*)&qw[((size_t)e * K + kabs + 0) * N + nbase + bn4];
            const int4 c1 = *(const int4*)&qw[((size_t)e * K + kabs + 1) * N + nbase + bn4];
            const int4 c2 = *(const int4*)&qw[((size_t)e * K + kabs + 2) * N + nbase + bn4];
            const int4 c3 = *(const int4*)&qw[((size_t)e * K + kabs + 3) * N + nbase + bn4];
            half4v q;
            q[0] = (_Float16)((c0.x - 8) * sc.x); q[1] = (_Float16)((c1.x - 8) * sc.x);
            q[2] = (_Float16)((c2.x - 8) * sc.x); q[3] = (_Float16)((c3.x - 8) * sc.x);
            *(half4v*)&Bs[bn4 + 0][bkb] = q;
            q[0] = (_Float16)((c0.y - 8) * sc.y); q[1] = (_Float16)((c1.y - 8) * sc.y);
            q[2] = (_Float16)((c2.y - 8) * sc.y); q[3] = (_Float16)((c3.y - 8) * sc.y);
            *(half4v*)&Bs[bn4 + 1][bkb] = q;
            q[0] = (_Float16)((c0.z - 8) * sc.z); q[1] = (_Float16)((c1.z - 8) * sc.z);
            q[2] = (_Float16)((c2.z - 8) * sc.z); q[3] = (_Float16)((c3.z - 8) * sc.z);
            *(half4v*)&Bs[bn4 + 2][bkb] = q;
            q[0] = (_Float16)((c0.w - 8) * sc.w); q[1] = (_Float16)((c1.w - 8) * sc.w);
            q[2] = (_Float16)((c2.w - 8) * sc.w); q[3] = (_Float16)((c3.w - 8) * sc.w);
            *(half4v*)&Bs[bn4 + 3][bkb] = q;
        }
        __syncthreads();
        // ---- MFMA: A[m][k=quad*8+j], B[k=quad*8+j][n], 16x16x32 ----
        half8v af[4], bf[4];
#pragma unroll
        for (int mi = 0; mi < 4; mi++)
            af[mi] = *(const half8v*)&As[wr + mi * 16 + lm][quad * 8];
#pragma unroll
        for (int ni = 0; ni < 4; ni++)
            bf[ni] = *(const half8v*)&Bs[wc + ni * 16 + lm][quad * 8];
#pragma unroll
        for (int mi = 0; mi < 4; mi++)
#pragma unroll
            for (int ni = 0; ni < 4; ni++)
                acc[mi][ni] = __builtin_amdgcn_mfma_f32_16x16x32_f16(af[mi], bf[ni], acc[mi][ni], 0, 0, 0);
    }

    const float gs = gsc[0];
    // ---- epilogue: D[row=quad*4+r][col=lm] per (mi,ni) ----
#pragma unroll
    for (int mi = 0; mi < 4; mi++) {
#pragma unroll
        for (int r = 0; r < 4; r++) {
            const int rl = wr + mi * 16 + quad * 4 + r;
            const int grow = mbase + rl;
            if (grow < cnt) {
                const int pr = rows_s[rl];
#pragma unroll
                for (int ni = 0; ni < 4; ni++) {
                    const int col = nbase + wc + ni * 16 + lm;
                    float v = acc[mi][ni][r] * gs;
                    if (UP) {
                        v = fmaxf(v, 0.f);
                        v = v * v * pw_s[rl];
                        store16[(size_t)pr * N + col] = (_Float16)v;
                    } else if (store16) {
                        store16[(size_t)pr * N + col] = (_Float16)v;
                    } else {
                        atomicAdd(&store32[(size_t)(pr >> 1) * N + col], v);
                    }
                }
            }
        }
    }
}

// ---------------- combine two pair rows -> fp32 out (ydown path) ----------------
__global__ __launch_bounds__(256) void finalize_kernel(
    const _Float16* __restrict__ ydown, float* __restrict__ out)
{
    int i = (blockIdx.x * 256 + threadIdx.x) * 4;   // [TOK*HD)
    int t = i >> 11;
    int h = i & 2047;
    size_t a = ((size_t)t << 12) + h;               // row 2t of [2T][2048]
    half4v ra = *(const half4v*)&ydown[a];
    half4v rb = *(const half4v*)&ydown[a + HD];
    float4 o;
    o.x = (float)ra[0] + (float)rb[0];
    o.y = (float)ra[1] + (float)rb[1];
    o.z = (float)ra[2] + (float)rb[2];
    o.w = (float)ra[3] + (float)rb[3];
    *(float4*)&out[i] = o;
}

extern "C" void kernel_launch(void* const* d_in, const int* in_sizes, int n_in,
                              void* d_out, int out_size, void* d_ws, size_t ws_size,
                              hipStream_t stream) {
    const float* x   = (const float*)d_in[0];
    const float* gw  = (const float*)d_in[1];
    const float* usc = (const float*)d_in[2];
    const float* ugs = (const float*)d_in[3];
    const float* dsc = (const float*)d_in[4];
    const float* dgs = (const float*)d_in[5];
    const int*   uq  = (const int*)d_in[6];
    const int*   dq  = (const int*)d_in[7];
    float* out = (float*)d_out;

    char* ws = (char*)d_ws;
    int*   counts   = (int*)(ws + 0);
    int*   pair_row = (int*)(ws + 4096);
    float* pair_w   = (float*)(ws + 4096 + (size_t)NE * CAP * 4);                 // 266240
    _Float16* xh    = (_Float16*)(ws + 528384);                                   // TOK*HD f16
    _Float16* act   = (_Float16*)(ws + 528384 + (size_t)TOK * HD * 2);            // 2*TOK*ID f16 @17305600
    _Float16* ydown = (_Float16*)(ws + 528384 + (size_t)TOK * HD * 2
                                  + (size_t)2 * TOK * ID * 2);                    // 2*TOK*HD f16 @34082816
    const size_t need_ydown = 34082816ull + (size_t)2 * TOK * HD * 2;             // 67.6 MB
    const bool use_ydown = ws_size >= need_ydown;

    hipMemsetAsync(counts, 0, 4096, stream);
    if (!use_ydown) hipMemsetAsync(out, 0, (size_t)TOK * HD * 4, stream);

    prep_kernel<<<(TOK * HD) / (256 * 8), 256, 0, stream>>>(x, xh);
    router_kernel<<<TOK, 256, 0, stream>>>(x, gw, counts, pair_row, pair_w);
    // up: M=cnt per expert, N=1024, K=2048
    gemm_kernel<ID, HD, true><<<dim3((CAP / 128) * (ID / 128), NE), 256, 0, stream>>>(
        xh, uq, usc, ugs, counts, pair_row, pair_w, act, nullptr);
    // down: N=2048, K=1024
    gemm_kernel<HD, ID, false><<<dim3((CAP / 128) * (HD / 128), NE), 256, 0, stream>>>(
        act, dq, dsc, dgs, counts, pair_row, pair_w,
        use_ydown ? ydown : nullptr, use_ydown ? nullptr : out);
    if (use_ydown)
        finalize_kernel<<<(TOK * HD) / 1024, 256, 0, stream>>>(ydown, out);
}